// Round 8
// baseline (1367.349 us; speedup 1.0000x reference)
//
#include <hip/hip_runtime.h>

// VectorQuantizer: M=32768 rows, N=8192 codes, D=256, fp32.
// Outputs flat fp32: [z_out 8388608][loss 1][idx 32768]
// idx = argmax zf.cb (l2-normalized); z_out = cb[idx]; loss = 1.25*mean((cb[idx]-zf)^2)
//
// R8: (1) scan occupancy 2->4 blocks/CU: grid 1024 = 128 row-blocks x 8 splits
// of 1024 codes, __launch_bounds__(256,4), LDS 128 KB/CU. Inner loop identical
// to R7 (proven). Barrier drains overlap across 4 independent blocks.
// (2) rescore: survivors scored by 8-lane groups in fp64 directly (coalesced
// 1 KB/survivor), cross-group argmin w/ first-index tie-break; serial fallback
// for ns>8. Kills the uniform 64-wide dot that kept "rest" at ~210 us.

#define M_ROWS 32768
#define N_CODES 8192
#define DIM 256
#define NSPLIT 8
#define NT 32             // 32-code tiles per split (1024 codes)
#define BUF_B 16384       // 32 code rows * 512B

typedef short v8s __attribute__((ext_vector_type(8)));
typedef float v4f __attribute__((ext_vector_type(4)));
typedef unsigned int uint;
typedef unsigned long long ull;

__device__ __forceinline__ unsigned short f2b(float f) {
    union { float f; unsigned u; } x; x.f = f;
    unsigned r = x.u + 0x7fffu + ((x.u >> 16) & 1u);   // RTNE
    return (unsigned short)(r >> 16);
}
__device__ __forceinline__ uint umax2(uint a, uint b) { return a > b ? a : b; }
__device__ __forceinline__ uint umin2(uint a, uint b) { return a < b ? a : b; }
__device__ __forceinline__ int swz(int u, int r) {    // 16B-unit XOR swizzle
    return (u & 24) | ((u ^ r) & 7);
}

// One wave per row: l2-normalize; emit fp32 (optional) + bf16 copies.
__global__ __launch_bounds__(256) void normalize_kernel(
        const float* __restrict__ src, float* __restrict__ dst,
        unsigned short* __restrict__ dstb, int nrows) {
    int wave = threadIdx.x >> 6, lane = threadIdx.x & 63;
    int r = blockIdx.x * 4 + wave;
    if (r >= nrows) return;
    float4 v = *(const float4*)(src + (size_t)r * DIM + lane * 4);
    float ss = v.x * v.x + v.y * v.y + v.z * v.z + v.w * v.w;
    #pragma unroll
    for (int o = 32; o; o >>= 1) ss += __shfl_xor(ss, o);
    float rinv = 1.0f / fmaxf(sqrtf(ss), 1e-12f);
    float4 o4; o4.x = v.x * rinv; o4.y = v.y * rinv; o4.z = v.z * rinv; o4.w = v.w * rinv;
    if (dst) *(float4*)(dst + (size_t)r * DIM + lane * 4) = o4;
    ushort4 b; b.x = f2b(o4.x); b.y = f2b(o4.y); b.z = f2b(o4.z); b.w = f2b(o4.w);
    *(ushort4*)(dstb + (size_t)r * DIM + lane * 4) = b;
}

// Scan: block = 256 rows x one split (1024 codes). Wave w owns rows
// [w*64, w*64+64) as 4 MFMA row-groups sharing each B fragment. 32-code tiles:
// 16 ds_read_b128 -> 64 MFMA per tile, 1 barrier. B staged to LDS through VGPRs
// (3-stage pipeline, double buffer), XOR-swizzled layout (R6/R7-proven).
// Top-2 keys per (row, residue16): key = fp32bits(score+2) & ~0x1FF | tile9.
__global__ __launch_bounds__(256, 4) void scan_kernel(
        const unsigned short* __restrict__ zfb,
        const unsigned short* __restrict__ cbb,
        uint* __restrict__ cand) {   // [row][256] = [row][8split][16res][2]
    __shared__ __align__(16) char lds[2 * BUF_B];
    int tid = threadIdx.x, w = tid >> 6, lane = tid & 63;
    int m = lane & 15, g = lane >> 4;
    int rb = blockIdx.x >> 3, split = blockIdx.x & 7;
    int r0 = rb * 256 + w * 64;
    const v4f C2 = {2.f, 2.f, 2.f, 2.f};

    // A fragments: A[m][k], k = c*32 + g*8 + j ; 4 row-groups of 16
    v8s a[4][8];
    #pragma unroll
    for (int h = 0; h < 4; ++h) {
        const unsigned short* ap = zfb + (size_t)(r0 + h * 16 + m) * DIM + g * 8;
        #pragma unroll
        for (int c = 0; c < 8; ++c) a[h][c] = *(const v8s*)(ap + c * 32);
    }

    // Staging: part i -> chunk q = 4w+i = code-row pair {2q, 2q+1}; 16 chunks/tile.
    const char* cb_base = (const char*)cbb + (size_t)split * 1024 * 512;
    const char* gp[4];
    int wo[4];
    #pragma unroll
    for (int i = 0; i < 4; ++i) {
        int q = 4 * w + i;
        int rr = 2 * q + (lane >> 5);
        int u = lane & 31;
        gp[i] = cb_base + q * 1024 + lane * 16;
        wo[i] = rr * 512 + swz(u, rr) * 16;
    }
    // ds_read offsets per K-chunk c (sub-tile 0; sub-tile 1 = +8192)
    int roff[8];
    #pragma unroll
    for (int c = 0; c < 8; ++c)
        roff[c] = m * 512 + swz(4 * c + g, m) * 16;

    // 3-stage pipeline prologue: load tile0 -> write buf0 -> load tile1
    uint4 st[4];
    #pragma unroll
    for (int i = 0; i < 4; ++i) { st[i] = *(const uint4*)gp[i]; gp[i] += BUF_B; }
    #pragma unroll
    for (int i = 0; i < 4; ++i) *(uint4*)(lds + wo[i]) = st[i];
    #pragma unroll
    for (int i = 0; i < 4; ++i) { st[i] = *(const uint4*)gp[i]; gp[i] += BUF_B; }

    uint top1[16], top2[16];
    #pragma unroll
    for (int i = 0; i < 16; ++i) { top1[i] = 0u; top2[i] = 0u; }

    for (int t = 0; t < NT; ++t) {
        __syncthreads();   // tile t's writes (all waves) visible; t-1 reads done
        if (t + 1 < NT) {
            char* nbuf = lds + ((t + 1) & 1) * BUF_B;
            #pragma unroll
            for (int i = 0; i < 4; ++i) *(uint4*)(nbuf + wo[i]) = st[i];
            if (t + 2 < NT) {
                #pragma unroll
                for (int i = 0; i < 4; ++i) { st[i] = *(const uint4*)gp[i]; gp[i] += BUF_B; }
            }
        }
        const char* cbuf = lds + (t & 1) * BUF_B;
        v4f acc[2][4];
        #pragma unroll
        for (int s2 = 0; s2 < 2; ++s2) {
            #pragma unroll
            for (int c = 0; c < 8; ++c) {
                v8s b = *(const v8s*)(cbuf + s2 * 8192 + roff[c]);
                #pragma unroll
                for (int h = 0; h < 4; ++h) {
                    v4f cin = (c == 0) ? C2 : acc[s2][h];   // C=const: no init movs
                    acc[s2][h] = __builtin_amdgcn_mfma_f32_16x16x32_bf16(a[h][c], b, cin, 0, 0, 0);
                }
            }
        }
        #pragma unroll
        for (int s2 = 0; s2 < 2; ++s2) {
            uint gt = (uint)(split * 64 + 2 * t + s2);      // 9-bit global tile id
            #pragma unroll
            for (int i = 0; i < 16; ++i) {
                float sc = acc[s2][i >> 2][i & 3];          // in [1,3]: bits sortable
                uint key = (__float_as_uint(sc) & 0xFFFFFE00u) | gt;
                uint old1 = top1[i];
                top1[i] = umax2(old1, key);
                top2[i] = umax2(top2[i], umin2(old1, key));
            }
        }
    }

    // C/D layout: row = g*4 + q, col(residue) = m
    #pragma unroll
    for (int i = 0; i < 16; ++i) {
        int h = i >> 2, q = i & 3;
        int row = r0 + h * 16 + g * 4 + q;
        uint2 v; v.x = top1[i]; v.y = top2[i];
        *(uint2*)(cand + (size_t)row * 256 + (split * 16 + m) * 2) = v;
    }
}

// One wave per row. Prune 256 candidates at margin 0.025 (> worst-case bf16
// key skew 0.0163), compact survivors via ballot-prefix into LDS. Survivor s
// scored by lanes 8s..8s+7: fp64 dot over 32 dims/lane (coalesced 1 KB/row),
// group XOR-reduce, cross-group argmin with first-index tie-break. Serial
// 64-lane fp64 fallback when ns > 8 (~1% rows). Emit z_out, idx, loss partial.
__global__ __launch_bounds__(256) void rescore_kernel(
        const float* __restrict__ x, const float* __restrict__ cb,
        const uint* __restrict__ cand, float* __restrict__ out,
        float* __restrict__ out_idx, double* __restrict__ lossp) {
    __shared__ float s_z[4][256];
    __shared__ int s_surv[4][256];
    int w = threadIdx.x >> 6, lane = threadIdx.x & 63;
    int r = blockIdx.x * 4 + w;
    float4 xv = *(const float4*)(x + (size_t)r * DIM + lane * 4);
    float ss = xv.x * xv.x + xv.y * xv.y + xv.z * xv.z + xv.w * xv.w;
    #pragma unroll
    for (int o = 32; o; o >>= 1) ss += __shfl_xor(ss, o);
    float rinv = 1.0f / fmaxf(sqrtf(ss), 1e-12f);
    float4 z4; z4.x = xv.x * rinv; z4.y = xv.y * rinv; z4.z = xv.z * rinv; z4.w = xv.w * rinv;
    *(float4*)(&s_z[w][lane * 4]) = z4;

    uint4 kk = *(const uint4*)(cand + (size_t)r * 256 + lane * 4);
    float kf0 = __uint_as_float(kk.x & 0xFFFFFE00u);
    float kf1 = __uint_as_float(kk.y & 0xFFFFFE00u);
    float kf2 = __uint_as_float(kk.z & 0xFFFFFE00u);
    float kf3 = __uint_as_float(kk.w & 0xFFFFFE00u);
    float kmax = fmaxf(fmaxf(kf0, kf1), fmaxf(kf2, kf3));
    #pragma unroll
    for (int o = 32; o; o >>= 1) kmax = fmaxf(kmax, __shfl_xor(kmax, o));
    float thr = kmax - 0.025f;
    bool p0 = kf0 >= thr, p1 = kf1 >= thr, p2 = kf2 >= thr, p3 = kf3 >= thr;
    ull m0 = __ballot(p0), m1 = __ballot(p1), m2 = __ballot(p2), m3 = __ballot(p3);
    ull lt = (1ull << lane) - 1ull;
    int b0 = 0, b1 = __popcll(m0), b2 = b1 + __popcll(m1), b3 = b2 + __popcll(m2);
    int ns = b3 + __popcll(m3);
    // lane's uint4 covers classes 2*lane (e0,e1) and 2*lane+1 (e2,e3);
    // residue = class & 15; class = split*16+res with res even/odd pairing.
    int res0 = (2 * lane) & 15, res1 = res0 + 1;
    int c0 = (int)(kk.x & 0x1FFu) * 16 + res0;
    int c1 = (int)(kk.y & 0x1FFu) * 16 + res0;
    int c2 = (int)(kk.z & 0x1FFu) * 16 + res1;
    int c3 = (int)(kk.w & 0x1FFu) * 16 + res1;
    if (p0) s_surv[w][b0 + __popcll(m0 & lt)] = c0;
    if (p1) s_surv[w][b1 + __popcll(m1 & lt)] = c1;
    if (p2) s_surv[w][b2 + __popcll(m2 & lt)] = c2;
    if (p3) s_surv[w][b3 + __popcll(m3 & lt)] = c3;
    // wave-private LDS region: same-wave DS ops are in program order; no barrier.

    int bestj;
    if (ns <= 8) {
        int s = lane >> 3, d8 = lane & 7;
        bool ga = s < ns;
        int j = s_surv[w][ga ? s : 0];
        const float* cp = cb + (size_t)j * DIM + d8 * 32;
        const float* zp = &s_z[w][d8 * 32];
        double acc = 0.0;
        #pragma unroll
        for (int i = 0; i < 8; ++i) {
            float4 c4 = *(const float4*)(cp + i * 4);
            float4 zq = *(const float4*)(zp + i * 4);
            acc += (double)c4.x * ((double)c4.x - 2.0 * (double)zq.x)
                 + (double)c4.y * ((double)c4.y - 2.0 * (double)zq.y)
                 + (double)c4.z * ((double)c4.z - 2.0 * (double)zq.z)
                 + (double)c4.w * ((double)c4.w - 2.0 * (double)zq.w);
        }
        #pragma unroll
        for (int o = 1; o < 8; o <<= 1) acc += __shfl_xor(acc, o);
        double dS = ga ? acc : 1e300;
        int jS = ga ? j : 0x7fffffff;
        #pragma unroll
        for (int o = 8; o < 64; o <<= 1) {
            double od = __shfl_xor(dS, o);
            int oj = __shfl_xor(jS, o);
            if (od < dS || (od == dS && oj < jS)) { dS = od; jS = oj; }
        }
        bestj = jS;
    } else {
        double bestd = 1e300; bestj = 0x7fffffff;
        for (int s = 0; s < ns; ++s) {
            int j = s_surv[w][s];
            float4 c4 = *(const float4*)(cb + (size_t)j * DIM + lane * 4);
            double p = (double)c4.x * ((double)c4.x - 2.0 * (double)z4.x)
                     + (double)c4.y * ((double)c4.y - 2.0 * (double)z4.y)
                     + (double)c4.z * ((double)c4.z - 2.0 * (double)z4.z)
                     + (double)c4.w * ((double)c4.w - 2.0 * (double)z4.w);
            #pragma unroll
            for (int o = 32; o; o >>= 1) p += __shfl_xor(p, o);
            if (p < bestd || (p == bestd && j < bestj)) { bestd = p; bestj = j; }
        }
    }
    float4 c4 = *(const float4*)(cb + (size_t)bestj * DIM + lane * 4);
    *(float4*)(out + (size_t)r * DIM + lane * 4) = c4;
    double dx = (double)c4.x - (double)z4.x, dy = (double)c4.y - (double)z4.y;
    double dz = (double)c4.z - (double)z4.z, dw = (double)c4.w - (double)z4.w;
    double lp = dx * dx + dy * dy + dz * dz + dw * dw;
    #pragma unroll
    for (int o = 32; o; o >>= 1) lp += __shfl_xor(lp, o);
    if (lane == 0) { lossp[r] = lp; out_idx[r] = (float)bestj; }
}

__global__ __launch_bounds__(256) void loss_kernel(
        const double* __restrict__ lossp, float* __restrict__ out) {
    __shared__ double sm[256];
    double s = 0.0;
    for (int i = threadIdx.x; i < M_ROWS; i += 256) s += lossp[i];
    sm[threadIdx.x] = s;
    __syncthreads();
    for (int o = 128; o; o >>= 1) {
        if ((int)threadIdx.x < o) sm[threadIdx.x] += sm[threadIdx.x + o];
        __syncthreads();
    }
    if (threadIdx.x == 0)
        out[0] = (float)(sm[0] * (1.25 / (double)(M_ROWS * DIM)));  // (BETA+1)*mean
}

extern "C" void kernel_launch(void* const* d_in, const int* in_sizes, int n_in,
                              void* d_out, int out_size, void* d_ws, size_t ws_size,
                              hipStream_t stream) {
    const float* x   = (const float*)d_in[0];   // 32*1024*256
    const float* emb = (const float*)d_in[1];   // 8192*256
    float* out = (float*)d_out;
    char* ws = (char*)d_ws;

    float*          cb    = (float*)(ws);                          // 8 MB
    unsigned short* cbb   = (unsigned short*)(ws + (8u  << 20));   // 4 MB
    unsigned short* zfb   = (unsigned short*)(ws + (12u << 20));   // 16 MB
    uint*           cand  = (uint*)(ws + (28u << 20));             // 32 MB
    double*         lossp = (double*)(ws + (60u << 20));           // 256 KB

    normalize_kernel<<<N_CODES / 4, 256, 0, stream>>>(emb, cb, cbb, N_CODES);
    normalize_kernel<<<M_ROWS / 4, 256, 0, stream>>>(x, nullptr, zfb, M_ROWS);
    scan_kernel<<<(M_ROWS / 256) * NSPLIT, 256, 0, stream>>>(zfb, cbb, cand);
    rescore_kernel<<<M_ROWS / 4, 256, 0, stream>>>(x, cb, cand,
                                                   out, out + ((size_t)M_ROWS * DIM + 1), lossp);
    loss_kernel<<<1, 256, 0, stream>>>(lossp, out + (size_t)M_ROWS * DIM);
}